// Round 10
// baseline (153.246 us; speedup 1.0000x reference)
//
#include <hip/hip_runtime.h>
#include <hip/hip_bf16.h>
#include <hip/hip_cooperative_groups.h>

namespace cg = cooperative_groups;

// Problem constants (B=1 folded out)
constexpr int T = 8;     // frames
constexpr int C = 128;   // input channels
constexpr int N = 4096;  // H*W positions
constexpr int F = 64;    // feature dim

typedef __bf16 bf16x8 __attribute__((ext_vector_type(8)));
typedef __bf16 bf16x4 __attribute__((ext_vector_type(4)));
typedef __bf16 bf16x2 __attribute__((ext_vector_type(2)));
typedef float  f32x4  __attribute__((ext_vector_type(4)));
typedef float  f32x16 __attribute__((ext_vector_type(16)));

constexpr int KSPLIT = 4;
constexpr int XS = 136;   // proj X^T LDS stride (272B rows)
constexpr int KS = 72;    // attn K/G LDS stride (144B rows)

// ===========================================================================
// FUSED cooperative kernel. Grid 512 x 512. LDS = 18432 B (union), so the
// runtime occupancy calc (sharedMemPerMP = 64 KB) gives >=2 blocks/CU and
// the 512-block cooperative launch is legal (R9's 34816 B LDS made it 1/CU
// -> launch rejected -> empty output).
//   Phase 0: zero d_out + W->bf16
//   Phase 1: proj, TWO-PASS staging through ONE X^T buffer:
//            stage X1 -> waves 0-3 load Q/G frags -> stage X2 -> waves 4-7
//            load K frags -> compute (waves 0-3: Q then G; waves 4-7: K).
//   Phase 2: attn, R8-verified body (bit-identical).
// ===========================================================================
union SMem {
    struct { __bf16 Xt[64 * XS]; } x;                       // 17408 B
    struct { __bf16 Kt[64 * KS]; __bf16 Gt[64 * KS]; } a;   // 18432 B
};

__global__ __launch_bounds__(512, 4) void fused_kernel(
    const float* __restrict__ x1, const float* __restrict__ x2,
    const float* __restrict__ W1, const float* __restrict__ W2,
    const float* __restrict__ W3,
    const float* __restrict__ b1, const float* __restrict__ b2,
    const float* __restrict__ b3,
    __bf16* __restrict__ Qb, __bf16* __restrict__ Kb, __bf16* __restrict__ Gw,
    __bf16* __restrict__ Wb, float* __restrict__ out)
{
    __shared__ SMem sm;
    const int tid = threadIdx.x;
    const int bid = blockIdx.x;

    // ================= Phase 0: zero out + W conversion =================
    {
        f32x4* o4 = (f32x4*)out;                // T*F*N/4 = 524288 f32x4
        const int base = bid * 1024 + tid;
        o4[base]       = (f32x4){0.f, 0.f, 0.f, 0.f};
        o4[base + 512] = (f32x4){0.f, 0.f, 0.f, 0.f};

        int i = bid * 512 + tid;                // first 24576 threads
        if (i < 3 * F * C) {
            int p = i >> 13, r = i & 8191;
            const float* W = (p == 0) ? W1 : (p == 1) ? W2 : W3;
            Wb[i] = (__bf16)W[r];
        }
    }
    cg::this_grid().sync();

    // ================= Phase 1: projections (two-pass staging) ==========
    {
        const int t  = bid >> 6;
        const int nb = bid & 63;
        const int n0 = nb * 64;
        const int wave = tid >> 6, lane = tid & 63;
        const int quad = lane >> 4, l16 = lane & 15;
        const int ng = tid & 15;               // n-block: n = ng*4 + j
        const int c0 = (tid >> 4) * 4;         // c-group 0..124
        const int rg = wave & 3;               // row-group for this wave

        // pass A: stage X1^T
        {
            const size_t base = ((size_t)t * C + c0) * (size_t)N + n0 + ng * 4;
            f32x4 v[4];
#pragma unroll
            for (int i = 0; i < 4; ++i) v[i] = *(const f32x4*)&x1[base + (size_t)i * N];
#pragma unroll
            for (int j = 0; j < 4; ++j) {
                bf16x4 o;
#pragma unroll
                for (int i = 0; i < 4; ++i) o[i] = (__bf16)v[i][j];
                *(bf16x4*)&sm.x.Xt[(ng * 4 + j) * XS + c0] = o;
            }
        }
        __syncthreads();

        bf16x8 a[4];
        if (wave < 4) {     // Q+G waves grab X1 fragments
#pragma unroll
            for (int cc = 0; cc < 4; ++cc)
                a[cc] = *(const bf16x8*)&sm.x.Xt[(rg * 16 + l16) * XS + cc * 32 + quad * 8];
        }
        __syncthreads();

        // pass B: stage X2^T over the same buffer
        {
            const size_t base = ((size_t)t * C + c0) * (size_t)N + n0 + ng * 4;
            f32x4 v[4];
#pragma unroll
            for (int i = 0; i < 4; ++i) v[i] = *(const f32x4*)&x2[base + (size_t)i * N];
#pragma unroll
            for (int j = 0; j < 4; ++j) {
                bf16x4 o;
#pragma unroll
                for (int i = 0; i < 4; ++i) o[i] = (__bf16)v[i][j];
                *(bf16x4*)&sm.x.Xt[(ng * 4 + j) * XS + c0] = o;
            }
        }
        __syncthreads();

        if (wave >= 4) {    // K waves grab X2 fragments
#pragma unroll
            for (int cc = 0; cc < 4; ++cc)
                a[cc] = *(const bf16x8*)&sm.x.Xt[(rg * 16 + l16) * XS + cc * 32 + quad * 8];
        }

        if (wave < 4) {
            // ---- Q: D[m=f][n'=n] = W1 · X1^T ----
            {
                const __bf16* W = Wb;          // p=0
                f32x4 acc[4];
#pragma unroll
                for (int ft = 0; ft < 4; ++ft) acc[ft] = (f32x4){0.f, 0.f, 0.f, 0.f};
#pragma unroll
                for (int cc = 0; cc < 4; ++cc)
#pragma unroll
                    for (int ft = 0; ft < 4; ++ft) {
                        bf16x8 wf = *(const bf16x8*)&W[(ft * 16 + l16) * C + cc * 32 + quad * 8];
                        acc[ft] = __builtin_amdgcn_mfma_f32_16x16x32_bf16(wf, a[cc], acc[ft], 0, 0, 0);
                    }
                const int n = n0 + rg * 16 + l16;
#pragma unroll
                for (int ft = 0; ft < 4; ++ft) {
                    const int f0 = ft * 16 + quad * 4;
                    f32x4 bv = *(const f32x4*)&b1[f0];
                    bf16x4 o;
#pragma unroll
                    for (int r = 0; r < 4; ++r) o[r] = (__bf16)(acc[ft][r] + bv[r]);
                    *(bf16x4*)&Qb[((size_t)t * N + n) * F + f0] = o;
                }
            }
            // ---- G: D[m=n][n'=f] = X1^T · W3 ----
            {
                const __bf16* W = Wb + (size_t)2 * F * C;
                f32x4 acc[4];
#pragma unroll
                for (int ft = 0; ft < 4; ++ft) acc[ft] = (f32x4){0.f, 0.f, 0.f, 0.f};
#pragma unroll
                for (int cc = 0; cc < 4; ++cc)
#pragma unroll
                    for (int ft = 0; ft < 4; ++ft) {
                        bf16x8 wf = *(const bf16x8*)&W[(ft * 16 + l16) * C + cc * 32 + quad * 8];
                        acc[ft] = __builtin_amdgcn_mfma_f32_16x16x32_bf16(a[cc], wf, acc[ft], 0, 0, 0);
                    }
                const int nr0 = n0 + rg * 16 + quad * 4;
#pragma unroll
                for (int ft = 0; ft < 4; ++ft) {
                    const int f = ft * 16 + l16;
                    const float bv = b3[f];
                    bf16x4 o;
#pragma unroll
                    for (int r = 0; r < 4; ++r) o[r] = (__bf16)(acc[ft][r] + bv);
                    *(bf16x4*)&Gw[((size_t)t * F + f) * (size_t)N + nr0] = o;
                }
            }
        } else {
            // ---- K: D[m=f][n'=n] = W2 · X2^T ----
            const __bf16* W = Wb + (size_t)F * C;
            f32x4 acc[4];
#pragma unroll
            for (int ft = 0; ft < 4; ++ft) acc[ft] = (f32x4){0.f, 0.f, 0.f, 0.f};
#pragma unroll
            for (int cc = 0; cc < 4; ++cc)
#pragma unroll
                for (int ft = 0; ft < 4; ++ft) {
                    bf16x8 wf = *(const bf16x8*)&W[(ft * 16 + l16) * C + cc * 32 + quad * 8];
                    acc[ft] = __builtin_amdgcn_mfma_f32_16x16x32_bf16(wf, a[cc], acc[ft], 0, 0, 0);
                }
            const int n = n0 + rg * 16 + l16;
#pragma unroll
            for (int ft = 0; ft < 4; ++ft) {
                const int f0 = ft * 16 + quad * 4;
                f32x4 bv = *(const f32x4*)&b2[f0];
                bf16x4 o;
#pragma unroll
                for (int r = 0; r < 4; ++r) o[r] = (__bf16)(acc[ft][r] + bv[r]);
                *(bf16x4*)&Kb[((size_t)t * N + n) * F + f0] = o;
            }
        }
    }
    cg::this_grid().sync();

    // ================= Phase 2: attention (R8 body, verified) ============
    {
        const int ks = bid & (KSPLIT - 1);
        const int qb = (bid / KSPLIT) & 15;    // N/256 = 16 q-blocks
        const int t  = bid / (KSPLIT * 16);
        const int q0 = qb * 256;

        const int wave = tid >> 6, lane = tid & 63;
        const int m32 = lane & 31, hi = lane >> 5;

        bf16x8 qf[4];
        {
            const __bf16* qrow = &Qb[((size_t)t * N + q0 + wave * 32 + m32) * F + hi * 8];
#pragma unroll
            for (int fc = 0; fc < 4; ++fc)
                qf[fc] = *(const bf16x8*)(qrow + fc * 16);
        }

        f32x16 oacc[2];
#pragma unroll
        for (int ft = 0; ft < 2; ++ft)
#pragma unroll
            for (int r = 0; r < 16; ++r) oacc[ft][r] = 0.f;

        const int kb_lo = ks * (N / 64 / KSPLIT);
        const int kb_hi = kb_lo + (N / 64 / KSPLIT);

        const int r8 = tid >> 3, c8 = (tid & 7) * 8;

        bf16x8 kv, gv;
        {
            const int k0 = kb_lo * 64;
            kv = *(const bf16x8*)&Kb[((size_t)t * N + k0 + r8) * F + c8];
            gv = *(const bf16x8*)&Gw[((size_t)t * F + r8) * (size_t)N + k0 + c8];
        }

        for (int kb = kb_lo; kb < kb_hi; ++kb) {
            __syncthreads();
            *(bf16x8*)&sm.a.Kt[r8 * KS + c8] = kv;
            *(bf16x8*)&sm.a.Gt[r8 * KS + c8] = gv;
            __syncthreads();

            if (kb + 1 < kb_hi) {
                const int k0 = (kb + 1) * 64;
                kv = *(const bf16x8*)&Kb[((size_t)t * N + k0 + r8) * F + c8];
                gv = *(const bf16x8*)&Gw[((size_t)t * F + r8) * (size_t)N + k0 + c8];
            }

            bf16x8 ps[4];
#pragma unroll
            for (int kt = 0; kt < 2; ++kt) {
                f32x16 s;
#pragma unroll
                for (int r = 0; r < 16; ++r) s[r] = 0.f;
                __builtin_amdgcn_s_setprio(1);
#pragma unroll
                for (int fc = 0; fc < 4; ++fc) {
                    bf16x8 kf = *(const bf16x8*)&sm.a.Kt[(kt * 32 + m32) * KS + fc * 16 + hi * 8];
                    s = __builtin_amdgcn_mfma_f32_32x32x16_bf16(kf, qf[fc], s, 0, 0, 0);
                }
                __builtin_amdgcn_s_setprio(0);
                unsigned P[8];
#pragma unroll
                for (int m = 0; m < 8; ++m) {
                    union { bf16x2 h; unsigned u; } pk;
                    pk.h[0] = (__bf16)fmaxf(s[2 * m], 0.f);
                    pk.h[1] = (__bf16)fmaxf(s[2 * m + 1], 0.f);
                    P[m] = pk.u;
                }
                asm("v_permlane32_swap_b32 %0, %1" : "+v"(P[0]), "+v"(P[2]));
                asm("v_permlane32_swap_b32 %0, %1" : "+v"(P[1]), "+v"(P[3]));
                asm("v_permlane32_swap_b32 %0, %1" : "+v"(P[4]), "+v"(P[6]));
                asm("v_permlane32_swap_b32 %0, %1" : "+v"(P[5]), "+v"(P[7]));
                union { unsigned u[4]; bf16x8 v; } lo, hiu;
                lo.u[0]  = P[0]; lo.u[1]  = P[1]; lo.u[2]  = P[2]; lo.u[3]  = P[3];
                hiu.u[0] = P[4]; hiu.u[1] = P[5]; hiu.u[2] = P[6]; hiu.u[3] = P[7];
                ps[kt * 2]     = lo.v;
                ps[kt * 2 + 1] = hiu.v;
            }

            __builtin_amdgcn_s_setprio(1);
#pragma unroll
            for (int ft = 0; ft < 2; ++ft)
#pragma unroll
                for (int kt = 0; kt < 2; ++kt)
#pragma unroll
                    for (int kc = 0; kc < 2; ++kc) {
                        bf16x8 gfr = *(const bf16x8*)&sm.a.Gt[(ft * 32 + m32) * KS +
                                                              kt * 32 + kc * 16 + hi * 8];
                        oacc[ft] = __builtin_amdgcn_mfma_f32_32x32x16_bf16(
                            gfr, ps[kt * 2 + kc], oacc[ft], 0, 0, 0);
                    }
            __builtin_amdgcn_s_setprio(0);
        }

        const int q = q0 + wave * 32 + m32;
#pragma unroll
        for (int ft = 0; ft < 2; ++ft)
#pragma unroll
            for (int r = 0; r < 16; ++r) {
                int f = ft * 32 + (r & 3) + 8 * (r >> 2) + 4 * hi;
                unsafeAtomicAdd(&out[((size_t)t * F + f) * (size_t)N + q], oacc[ft][r]);
            }
    }
}

// ===========================================================================
// FALLBACK path: R8's verified 3-kernel pipeline (151.9 us total).
// ===========================================================================
__global__ __launch_bounds__(256) void setup_kernel(
    const float* __restrict__ W1, const float* __restrict__ W2,
    const float* __restrict__ W3, __bf16* __restrict__ Wb,
    float* __restrict__ out)
{
    int i = blockIdx.x * 256 + threadIdx.x;
    ((f32x4*)out)[i] = (f32x4){0.f, 0.f, 0.f, 0.f};
    if (i < 3 * F * C) {
        int p = i >> 13, r = i & 8191;
        const float* W = (p == 0) ? W1 : (p == 1) ? W2 : W3;
        Wb[i] = (__bf16)W[r];
    }
}

__global__ __launch_bounds__(256) void proj_kernel(
    const float* __restrict__ x1, const float* __restrict__ x2,
    const __bf16* __restrict__ Wb,
    const float* __restrict__ b1, const float* __restrict__ b2,
    const float* __restrict__ b3,
    __bf16* __restrict__ Qb, __bf16* __restrict__ Kb, __bf16* __restrict__ Gw)
{
    const int pj = blockIdx.y;        // 0=Q, 1=K, 2=G
    const int t  = blockIdx.x >> 6;
    const int nb = blockIdx.x & 63;
    const int n0 = nb * 64;

    __shared__ __bf16 Xt[64 * XS];
    const float* X = (pj == 1) ? x2 : x1;

    const int tid = threadIdx.x;
    const int ng  = tid & 15;
    const int cgi = tid >> 4;

#pragma unroll
    for (int pass = 0; pass < 2; ++pass) {
        const int c0 = cgi * 4 + pass * 64;
        const size_t base = ((size_t)t * C + c0) * (size_t)N + n0 + ng * 4;
        f32x4 v[4];
#pragma unroll
        for (int i = 0; i < 4; ++i) v[i] = *(const f32x4*)&X[base + (size_t)i * N];
#pragma unroll
        for (int j = 0; j < 4; ++j) {
            bf16x4 o;
#pragma unroll
            for (int i = 0; i < 4; ++i) o[i] = (__bf16)v[i][j];
            *(bf16x4*)&Xt[(ng * 4 + j) * XS + c0] = o;
        }
    }
    __syncthreads();

    const int wave = tid >> 6, lane = tid & 63;
    const int quad = lane >> 4, l16 = lane & 15;

    bf16x8 a[4];
#pragma unroll
    for (int cc = 0; cc < 4; ++cc)
        a[cc] = *(const bf16x8*)&Xt[(wave * 16 + l16) * XS + cc * 32 + quad * 8];

    const __bf16* W = Wb + (size_t)pj * F * C;

    if (pj < 2) {
        const float* bias = pj ? b2 : b1;
        __bf16*      O    = pj ? Kb : Qb;
        f32x4 acc[4];
#pragma unroll
        for (int ft = 0; ft < 4; ++ft) acc[ft] = (f32x4){0.f, 0.f, 0.f, 0.f};
#pragma unroll
        for (int cc = 0; cc < 4; ++cc)
#pragma unroll
            for (int ft = 0; ft < 4; ++ft) {
                bf16x8 wf = *(const bf16x8*)&W[(ft * 16 + l16) * C + cc * 32 + quad * 8];
                acc[ft] = __builtin_amdgcn_mfma_f32_16x16x32_bf16(wf, a[cc], acc[ft], 0, 0, 0);
            }
        const int n = n0 + wave * 16 + l16;
#pragma unroll
        for (int ft = 0; ft < 4; ++ft) {
            const int f0 = ft * 16 + quad * 4;
            f32x4 bv = *(const f32x4*)&bias[f0];
            bf16x4 o;
#pragma unroll
            for (int r = 0; r < 4; ++r) o[r] = (__bf16)(acc[ft][r] + bv[r]);
            *(bf16x4*)&O[((size_t)t * N + n) * F + f0] = o;
        }
    } else {
        f32x4 acc[4];
#pragma unroll
        for (int ft = 0; ft < 4; ++ft) acc[ft] = (f32x4){0.f, 0.f, 0.f, 0.f};
#pragma unroll
        for (int cc = 0; cc < 4; ++cc)
#pragma unroll
            for (int ft = 0; ft < 4; ++ft) {
                bf16x8 wf = *(const bf16x8*)&W[(ft * 16 + l16) * C + cc * 32 + quad * 8];
                acc[ft] = __builtin_amdgcn_mfma_f32_16x16x32_bf16(a[cc], wf, acc[ft], 0, 0, 0);
            }
        const int nr0 = n0 + wave * 16 + quad * 4;
#pragma unroll
        for (int ft = 0; ft < 4; ++ft) {
            const int f = ft * 16 + l16;
            const float bv = b3[f];
            bf16x4 o;
#pragma unroll
            for (int r = 0; r < 4; ++r) o[r] = (__bf16)(acc[ft][r] + bv);
            *(bf16x4*)&Gw[((size_t)t * F + f) * (size_t)N + nr0] = o;
        }
    }
}

__global__ __launch_bounds__(512, 4) void attn_kernel(
    const __bf16* __restrict__ Qb, const __bf16* __restrict__ Kb,
    const __bf16* __restrict__ Gw, float* __restrict__ out)
{
    const int ks = blockIdx.x & (KSPLIT - 1);
    const int qb = (blockIdx.x / KSPLIT) & 15;
    const int t  = blockIdx.x / (KSPLIT * 16);
    const int q0 = qb * 256;

    __shared__ __bf16 Kt[64 * KS];
    __shared__ __bf16 Gt[64 * KS];

    const int tid = threadIdx.x, wave = tid >> 6, lane = tid & 63;
    const int m32 = lane & 31, hi = lane >> 5;

    bf16x8 qf[4];
    {
        const __bf16* qrow = &Qb[((size_t)t * N + q0 + wave * 32 + m32) * F + hi * 8];
#pragma unroll
        for (int fc = 0; fc < 4; ++fc)
            qf[fc] = *(const bf16x8*)(qrow + fc * 16);
    }

    f32x16 oacc[2];
#pragma unroll
    for (int ft = 0; ft < 2; ++ft)
#pragma unroll
        for (int r = 0; r < 16; ++r) oacc[ft][r] = 0.f;

    const int kb_lo = ks * (N / 64 / KSPLIT);
    const int kb_hi = kb_lo + (N / 64 / KSPLIT);

    const int r8 = tid >> 3, c8 = (tid & 7) * 8;

    bf16x8 kv, gv;
    {
        const int k0 = kb_lo * 64;
        kv = *(const bf16x8*)&Kb[((size_t)t * N + k0 + r8) * F + c8];
        gv = *(const bf16x8*)&Gw[((size_t)t * F + r8) * (size_t)N + k0 + c8];
    }

    for (int kb = kb_lo; kb < kb_hi; ++kb) {
        __syncthreads();
        *(bf16x8*)&Kt[r8 * KS + c8] = kv;
        *(bf16x8*)&Gt[r8 * KS + c8] = gv;
        __syncthreads();

        if (kb + 1 < kb_hi) {
            const int k0 = (kb + 1) * 64;
            kv = *(const bf16x8*)&Kb[((size_t)t * N + k0 + r8) * F + c8];
            gv = *(const bf16x8*)&Gw[((size_t)t * F + r8) * (size_t)N + k0 + c8];
        }

        bf16x8 ps[4];
#pragma unroll
        for (int kt = 0; kt < 2; ++kt) {
            f32x16 s;
#pragma unroll
            for (int r = 0; r < 16; ++r) s[r] = 0.f;
            __builtin_amdgcn_s_setprio(1);
#pragma unroll
            for (int fc = 0; fc < 4; ++fc) {
                bf16x8 kf = *(const bf16x8*)&Kt[(kt * 32 + m32) * KS + fc * 16 + hi * 8];
                s = __builtin_amdgcn_mfma_f32_32x32x16_bf16(kf, qf[fc], s, 0, 0, 0);
            }
            __builtin_amdgcn_s_setprio(0);
            unsigned P[8];
#pragma unroll
            for (int m = 0; m < 8; ++m) {
                union { bf16x2 h; unsigned u; } pk;
                pk.h[0] = (__bf16)fmaxf(s[2 * m], 0.f);
                pk.h[1] = (__bf16)fmaxf(s[2 * m + 1], 0.f);
                P[m] = pk.u;
            }
            asm("v_permlane32_swap_b32 %0, %1" : "+v"(P[0]), "+v"(P[2]));
            asm("v_permlane32_swap_b32 %0, %1" : "+v"(P[1]), "+v"(P[3]));
            asm("v_permlane32_swap_b32 %0, %1" : "+v"(P[4]), "+v"(P[6]));
            asm("v_permlane32_swap_b32 %0, %1" : "+v"(P[5]), "+v"(P[7]));
            union { unsigned u[4]; bf16x8 v; } lo, hiu;
            lo.u[0]  = P[0]; lo.u[1]  = P[1]; lo.u[2]  = P[2]; lo.u[3]  = P[3];
            hiu.u[0] = P[4]; hiu.u[1] = P[5]; hiu.u[2] = P[6]; hiu.u[3] = P[7];
            ps[kt * 2]     = lo.v;
            ps[kt * 2 + 1] = hiu.v;
        }

        __builtin_amdgcn_s_setprio(1);
#pragma unroll
        for (int ft = 0; ft < 2; ++ft)
#pragma unroll
            for (int kt = 0; kt < 2; ++kt)
#pragma unroll
                for (int kc = 0; kc < 2; ++kc) {
                    bf16x8 gfr = *(const bf16x8*)&Gt[(ft * 32 + m32) * KS +
                                                     kt * 32 + kc * 16 + hi * 8];
                    oacc[ft] = __builtin_amdgcn_mfma_f32_32x32x16_bf16(
                        gfr, ps[kt * 2 + kc], oacc[ft], 0, 0, 0);
                }
        __builtin_amdgcn_s_setprio(0);
    }

    const int q = q0 + wave * 32 + m32;
#pragma unroll
    for (int ft = 0; ft < 2; ++ft)
#pragma unroll
        for (int r = 0; r < 16; ++r) {
            int f = ft * 32 + (r & 3) + 8 * (r >> 2) + 4 * hi;
            unsafeAtomicAdd(&out[((size_t)t * F + f) * (size_t)N + q], oacc[ft][r]);
        }
}

// ---------------------------------------------------------------------------
extern "C" void kernel_launch(void* const* d_in, const int* in_sizes, int n_in,
                              void* d_out, int out_size, void* d_ws, size_t ws_size,
                              hipStream_t stream) {
    const float* x1 = (const float*)d_in[0];
    const float* x2 = (const float*)d_in[1];
    const float* W1 = (const float*)d_in[2];
    const float* b1 = (const float*)d_in[3];
    const float* W2 = (const float*)d_in[4];
    const float* b2 = (const float*)d_in[5];
    const float* W3 = (const float*)d_in[6];
    const float* b3 = (const float*)d_in[7];
    float* out = (float*)d_out;

    __bf16* Qb = (__bf16*)d_ws;
    __bf16* Kb = Qb + (size_t)T * N * F;
    __bf16* Gw = Kb + (size_t)T * N * F;
    __bf16* Wb = Gw + (size_t)T * N * F;

    // coop_ok: -1 unknown, 0 failed (use fallback), 1 works.
    static int coop_ok = -1;
    hipStreamCaptureStatus cap = hipStreamCaptureStatusNone;
    (void)hipStreamIsCapturing(stream, &cap);
    const bool capturing = (cap != hipStreamCaptureStatusNone);
    // Probe eagerly (non-capture) so a failing coop launch can't poison a
    // graph capture; in capture, only use coop if the eager probe succeeded.
    const bool attempt = capturing ? (coop_ok == 1) : (coop_ok != 0);

    if (attempt) {
        void* args[] = {&x1, &x2, &W1, &W2, &W3, &b1, &b2, &b3,
                        &Qb, &Kb, &Gw, &Wb, &out};
        hipError_t e = hipLaunchCooperativeKernel((void*)fused_kernel,
                                                  dim3(512), dim3(512),
                                                  args, 0, stream);
        if (e == hipSuccess) {
            if (!capturing) coop_ok = 1;
            return;
        }
        (void)hipGetLastError();   // clear non-sticky launch error
        if (!capturing) coop_ok = 0;
    }

    // Fallback: verified R8 3-kernel pipeline.
    setup_kernel<<<dim3(T * F * N / 4 / 256), dim3(256), 0, stream>>>(
        W1, W2, W3, Wb, out);
    proj_kernel<<<dim3(T * (N / 64), 3), dim3(256), 0, stream>>>(
        x1, x2, Wb, b1, b2, b3, Qb, Kb, Gw);
    attn_kernel<<<dim3(T * 16 * KSPLIT), dim3(512), 0, stream>>>(Qb, Kb, Gw, out);
}